// Round 1
// baseline (171.835 us; speedup 1.0000x reference)
//
#include <hip/hip_runtime.h>

// Problem constants
// x: [128][256][256][3] fp32  (b, y, xx, ch) row-major
// C: [768][4][256][4]   fp32  -> viewed as [3072 rows][1024 cols]
// out: [128][256][4][8][8] fp32 = S_x[b, h*8+w] * S_C[k*4+l]
//
// einsum('bcshw,ijkl->bklhw') has no shared labels => full factorization:
//   S_x[b,h,w] = sum over all 3072 (ci,si) = sum_{p1,p2,ch} x[b, p1*8+h, p2*8+w, ch]
//   S_C[k,l]   = sum_{i,j} C[i,j,k,l]
//   out        = outer product

// ---------------- Kernel 1: column-sum of C ----------------
// grid (4, 96), block 256. Each block: 256 cols x 32 rows partial, atomicAdd.
__global__ __launch_bounds__(256) void reduce_C_kernel(const float* __restrict__ C,
                                                       float* __restrict__ sC) {
    const int col  = blockIdx.x * 256 + threadIdx.x;   // [0,1024)
    const int row0 = blockIdx.y * 32;                  // grid.y = 96 -> 3072 rows
    const float* p = C + (size_t)row0 * 1024 + col;
    float s = 0.f;
#pragma unroll
    for (int r = 0; r < 32; ++r) s += p[r * 1024];
    atomicAdd(sC + col, s);
}

// ---------------- Kernel 2: strided pixel-position sum of x ----------------
// x rows are 768 floats (256 px * 3ch). w-bin = pixel%8 has period 24 floats.
// Thread t in [0,192) reads positions t + 192*it -> fixed w = (t%24)/3.
// Block handles one image b and 32 consecutive rows; rows grouped by h=y%8 so
// acc[] indexing is static. Epilogue: LDS reduce 192x8 -> 64 bins, atomicAdd.
__global__ __launch_bounds__(192) void reduce_x_kernel(const float* __restrict__ x,
                                                       float* __restrict__ sx) {
    const int b  = blockIdx.y;            // [0,128)
    const int y0 = blockIdx.x * 32;       // grid.x = 8 -> 256 rows
    const int t  = threadIdx.x;           // [0,192)
    const float* base = x + ((size_t)b * 256 + y0) * 768;

    float acc[8];
#pragma unroll
    for (int h = 0; h < 8; ++h) acc[h] = 0.f;

#pragma unroll
    for (int h = 0; h < 8; ++h) {
#pragma unroll
        for (int j = 0; j < 4; ++j) {               // rows y0+h+8j, all have y%8==h
            const float* rowp = base + (size_t)(h + 8 * j) * 768;
#pragma unroll
            for (int it = 0; it < 4; ++it)          // 4*192 = 768 floats/row
                acc[h] += rowp[it * 192 + t];
        }
    }

    __shared__ float lds[192][8];
#pragma unroll
    for (int h = 0; h < 8; ++h) lds[t][h] = acc[h];
    __syncthreads();

    if (t < 64) {
        const int h = t >> 3, w = t & 7;
        float s = 0.f;
#pragma unroll
        for (int g = 0; g < 8; ++g)
#pragma unroll
            for (int c = 0; c < 3; ++c)
                s += lds[g * 24 + w * 3 + c][h];
        atomicAdd(sx + b * 64 + t, s);   // bin = h*8+w == t
    }
}

// ---------------- Kernel 3: outer-product expansion ----------------
// out[b, kl, hw] = sx[b][hw] * sC[kl]; float4 over hw (16 float4 per kl).
// grid (64, 128), block 256: per b, 16384 float4s.
__global__ __launch_bounds__(256) void expand_kernel(const float* __restrict__ sx,
                                                     const float* __restrict__ sC,
                                                     float4* __restrict__ out) {
    const int b   = blockIdx.y;
    const int idx = blockIdx.x * 256 + threadIdx.x;  // [0, 16384)
    const int hw4 = idx & 15;
    const int kl  = idx >> 4;
    const float4 v = ((const float4*)(sx + b * 64))[hw4];
    const float  s = sC[kl];
    float4 r;
    r.x = v.x * s; r.y = v.y * s; r.z = v.z * s; r.w = v.w * s;
    out[(size_t)b * 16384 + idx] = r;
}

extern "C" void kernel_launch(void* const* d_in, const int* in_sizes, int n_in,
                              void* d_out, int out_size, void* d_ws, size_t ws_size,
                              hipStream_t stream) {
    const float* x = (const float*)d_in[0];   // 25,165,824 floats
    const float* C = (const float*)d_in[1];   //  3,145,728 floats
    float* out = (float*)d_out;               //  8,388,608 floats

    float* sC = (float*)d_ws;                 // 1024 floats
    float* sx = (float*)d_ws + 1024;          // 8192 floats

    // ws is re-poisoned to 0xAA before every timed launch -> zero accumulators.
    hipMemsetAsync(d_ws, 0, (1024 + 8192) * sizeof(float), stream);

    reduce_C_kernel<<<dim3(4, 96),  256, 0, stream>>>(C, sC);
    reduce_x_kernel<<<dim3(8, 128), 192, 0, stream>>>(x, sx);
    expand_kernel<<<dim3(64, 128),  256, 0, stream>>>(sx, sC, (float4*)out);
}